// Round 1
// baseline (983.619 us; speedup 1.0000x reference)
//
#include <hip/hip_runtime.h>
#include <math.h>

// Shapes (fixed by the problem)
// H=8, D=256, HD=32, B=16, Q=512, S1=64, NTASK=448

// ---------------------------------------------------------------------------
// Projection GEMM: out_p[h][b][n][e] = sum_d h_fea[b, q_off+n, d] * Wp[h, d, e]
// A: 64-row tile of h_fea (rows contiguous within one b), cols = proj*256 + h*32 + e
// ---------------------------------------------------------------------------
__global__ __launch_bounds__(256)
void proj_gemm(const float* __restrict__ A,
               const float* __restrict__ W0, const float* __restrict__ W1p,
               const float* __restrict__ W2p, const float* __restrict__ W3p,
               float* __restrict__ O0, float* __restrict__ O1,
               float* __restrict__ O2, float* __restrict__ O3,
               int q_off, int rows_per_b, int tiles_per_b)
{
    __shared__ float Asub[32][68];
    __shared__ float Bsub[32][68];
    const int tid = (int)threadIdx.x;
    const int b  = (int)blockIdx.x / tiles_per_b;
    const int n0 = ((int)blockIdx.x % tiles_per_b) * 64;
    const int p  = (int)blockIdx.y >> 2;
    const int cb = ((int)blockIdx.y & 3) * 64;   // col base within proj (0..255)
    const float* Wp = (p == 0) ? W0 : (p == 1) ? W1p : (p == 2) ? W2p : W3p;
    float* Op       = (p == 0) ? O0 : (p == 1) ? O1 : (p == 2) ? O2 : O3;

    const int tx = tid & 15, ty = tid >> 4;
    float acc[4][4] = {};
    const float* Arow = A + (size_t)(b * 512 + q_off + n0) * 256;

    for (int k0 = 0; k0 < 256; k0 += 32) {
        #pragma unroll
        for (int i = 0; i < 8; ++i) {
            int idx = tid + 256 * i;
            int kk = idx & 31, r = idx >> 5;
            Asub[kk][r] = Arow[(size_t)r * 256 + k0 + kk];
        }
        #pragma unroll
        for (int i = 0; i < 8; ++i) {
            int idx = tid + 256 * i;
            int c = idx & 63, kk = idx >> 6;
            int cg = cb + c;
            int h = cg >> 5, e = cg & 31;
            Bsub[kk][c] = Wp[(size_t)(h * 256 + k0 + kk) * 32 + e];
        }
        __syncthreads();
        #pragma unroll
        for (int kk = 0; kk < 32; ++kk) {
            float4 a4 = *(const float4*)&Asub[kk][ty * 4];
            float4 b4 = *(const float4*)&Bsub[kk][tx * 4];
            acc[0][0] += a4.x * b4.x; acc[0][1] += a4.x * b4.y; acc[0][2] += a4.x * b4.z; acc[0][3] += a4.x * b4.w;
            acc[1][0] += a4.y * b4.x; acc[1][1] += a4.y * b4.y; acc[1][2] += a4.y * b4.z; acc[1][3] += a4.y * b4.w;
            acc[2][0] += a4.z * b4.x; acc[2][1] += a4.z * b4.y; acc[2][2] += a4.z * b4.z; acc[2][3] += a4.z * b4.w;
            acc[3][0] += a4.w * b4.x; acc[3][1] += a4.w * b4.y; acc[3][2] += a4.w * b4.z; acc[3][3] += a4.w * b4.w;
        }
        __syncthreads();
    }
    const int cg = cb + tx * 4;
    const int h = cg >> 5, e = cg & 31;
    #pragma unroll
    for (int i = 0; i < 4; ++i) {
        int n = n0 + ty * 4 + i;
        float4 v = make_float4(acc[i][0], acc[i][1], acc[i][2], acc[i][3]);
        *(float4*)&Op[(((size_t)h * 16 + b) * rows_per_b + n) * 32 + e] = v;
    }
}

// ---------------------------------------------------------------------------
// Output projection: C[bq][d] = sum_c HEADS[bq][c] * W_out_flat[c][d]
// ---------------------------------------------------------------------------
__global__ __launch_bounds__(256)
void out_gemm(const float* __restrict__ A, const float* __restrict__ Bm,
              float* __restrict__ C)
{
    __shared__ float Asub[32][68];
    __shared__ float Bsub[32][68];
    const int tid = (int)threadIdx.x;
    const int row0 = (int)blockIdx.x * 64;
    const int col0 = (int)blockIdx.y * 64;
    const int tx = tid & 15, ty = tid >> 4;
    float acc[4][4] = {};

    for (int k0 = 0; k0 < 256; k0 += 32) {
        #pragma unroll
        for (int i = 0; i < 8; ++i) {
            int idx = tid + 256 * i;
            int kk = idx & 31, r = idx >> 5;
            Asub[kk][r] = A[(size_t)(row0 + r) * 256 + k0 + kk];
        }
        #pragma unroll
        for (int i = 0; i < 8; ++i) {
            int idx = tid + 256 * i;
            int c = idx & 63, kk = idx >> 6;
            Bsub[kk][c] = Bm[(size_t)(k0 + kk) * 256 + col0 + c];
        }
        __syncthreads();
        #pragma unroll
        for (int kk = 0; kk < 32; ++kk) {
            float4 a4 = *(const float4*)&Asub[kk][ty * 4];
            float4 b4 = *(const float4*)&Bsub[kk][tx * 4];
            acc[0][0] += a4.x * b4.x; acc[0][1] += a4.x * b4.y; acc[0][2] += a4.x * b4.z; acc[0][3] += a4.x * b4.w;
            acc[1][0] += a4.y * b4.x; acc[1][1] += a4.y * b4.y; acc[1][2] += a4.y * b4.z; acc[1][3] += a4.y * b4.w;
            acc[2][0] += a4.z * b4.x; acc[2][1] += a4.z * b4.y; acc[2][2] += a4.z * b4.z; acc[2][3] += a4.z * b4.w;
            acc[3][0] += a4.w * b4.x; acc[3][1] += a4.w * b4.y; acc[3][2] += a4.w * b4.z; acc[3][3] += a4.w * b4.w;
        }
        __syncthreads();
    }
    #pragma unroll
    for (int i = 0; i < 4; ++i) {
        float4 v = make_float4(acc[i][0], acc[i][1], acc[i][2], acc[i][3]);
        *(float4*)&C[(size_t)(row0 + ty * 4 + i) * 256 + col0 + tx * 4] = v;
    }
}

// ---------------------------------------------------------------------------
// Fused attend: scores (QK^T) -> fuse-MLP with aux -> online softmax -> A@V
// Q/K/V buffers laid out [h][16][rows][32]. heads laid out [b][512][h*32+e].
// Block: 16 query rows (one b). TILE_M = 16 keys per step.
// Thread roles: score/AV: (n=tid>>4, h=(tid>>1)&7, half=tid&1); MLP: 1 position.
// ---------------------------------------------------------------------------
__global__ __launch_bounds__(256)
void attend_kernel(const float* __restrict__ Qb, const float* __restrict__ Kb,
                   const float* __restrict__ Vb, const float* __restrict__ aux,
                   const float* __restrict__ W1g, const float* __restrict__ b1g,
                   const float* __restrict__ W2g, const float* __restrict__ b2g,
                   float* __restrict__ heads,
                   int NR, int ML, int n_off, int m_off, int q_off, int accum)
{
    __shared__ float Ks[128 * 36];     // [mm*8+h][36]
    __shared__ float Vs[128 * 36];
    __shared__ float Sx[16 * 132];     // [n][mm*8+h], row stride 132
    __shared__ float Wl[408];          // W1 (256) | W2 (128) | b1 (16) | b2 (8)
    __shared__ float Mst[128], Lst[128], Alph[128];

    const int tid  = (int)threadIdx.x;
    const int n0g  = (int)blockIdx.x * 16;
    const int b    = (int)blockIdx.y;

    // Weights / state to LDS
    Wl[tid] = W1g[tid];                 // 256 threads == 256 W1 elems
    if (tid < 128) Wl[256 + tid] = W2g[tid];
    if (tid < 16)  Wl[384 + tid] = b1g[tid];
    if (tid < 8)   Wl[400 + tid] = b2g[tid];
    if (tid < 128) { Mst[tid] = -INFINITY; Lst[tid] = 0.f; }

    const int sn  = tid >> 4;          // query row within tile (0..15)
    const int sh  = (tid >> 1) & 7;    // head
    const int smh = tid & 1;           // m-half (scores) / e-half (AV)

    // Q row for (sn, sh) into registers (reused across all m-steps)
    float qreg[32];
    {
        const float* qsrc = Qb + (((size_t)sh * 16 + b) * NR + n0g + sn) * 32;
        #pragma unroll
        for (int i = 0; i < 8; ++i) {
            float4 t = *(const float4*)(qsrc + i * 4);
            qreg[i*4+0] = t.x; qreg[i*4+1] = t.y; qreg[i*4+2] = t.z; qreg[i*4+3] = t.w;
        }
    }

    float acc[16];
    #pragma unroll
    for (int i = 0; i < 16; ++i) acc[i] = 0.f;

    const int mlp_n = tid >> 4, mlp_m = tid & 15;
    __syncthreads();

    for (int m0 = 0; m0 < ML; m0 += 16) {
        // ---- stage K, V tiles ----
        {
            int row = tid >> 1, half = tid & 1;
            int mm = row >> 3, h = row & 7;
            const float* ksrc = Kb + (((size_t)h * 16 + b) * ML + m0 + mm) * 32 + half * 16;
            const float* vsrc = Vb + (((size_t)h * 16 + b) * ML + m0 + mm) * 32 + half * 16;
            float* kd = &Ks[(mm * 8 + h) * 36 + half * 16];
            float* vd = &Vs[(mm * 8 + h) * 36 + half * 16];
            #pragma unroll
            for (int i = 0; i < 4; ++i) *(float4*)(kd + i * 4) = *(const float4*)(ksrc + i * 4);
            #pragma unroll
            for (int i = 0; i < 4; ++i) *(float4*)(vd + i * 4) = *(const float4*)(vsrc + i * 4);
        }
        __syncthreads();

        // ---- scores: s[n, mm, h] = Q[n,h] . K[mm,h] ----
        #pragma unroll
        for (int mm8 = 0; mm8 < 8; ++mm8) {
            int mm = smh * 8 + mm8;
            const float* kr = &Ks[(mm * 8 + sh) * 36];
            float s = 0.f;
            #pragma unroll
            for (int i = 0; i < 8; ++i) {
                float4 kv = *(const float4*)(kr + i * 4);
                s += qreg[i*4+0] * kv.x + qreg[i*4+1] * kv.y
                   + qreg[i*4+2] * kv.z + qreg[i*4+3] * kv.w;
            }
            Sx[sn * 132 + mm * 8 + sh] = s;
        }
        __syncthreads();

        // ---- fuse MLP: one (n, m) position per thread ----
        {
            float x[16];
            {
                const float4 s0 = *(const float4*)&Sx[mlp_n * 132 + mlp_m * 8];
                const float4 s1 = *(const float4*)&Sx[mlp_n * 132 + mlp_m * 8 + 4];
                x[0]=s0.x; x[1]=s0.y; x[2]=s0.z; x[3]=s0.w;
                x[4]=s1.x; x[5]=s1.y; x[6]=s1.z; x[7]=s1.w;
            }
            #pragma unroll
            for (int h = 0; h < 8; ++h)
                x[8 + h] = aux[(((size_t)h * 16 + b) * 512 + (n_off + n0g + mlp_n)) * 512
                               + (m_off + m0 + mlp_m)];
            float hid[16];
            {
                const float4 ba = *(const float4*)&Wl[384];
                const float4 bb = *(const float4*)&Wl[388];
                const float4 bc = *(const float4*)&Wl[392];
                const float4 bd = *(const float4*)&Wl[396];
                hid[0]=ba.x; hid[1]=ba.y; hid[2]=ba.z; hid[3]=ba.w;
                hid[4]=bb.x; hid[5]=bb.y; hid[6]=bb.z; hid[7]=bb.w;
                hid[8]=bc.x; hid[9]=bc.y; hid[10]=bc.z; hid[11]=bc.w;
                hid[12]=bd.x; hid[13]=bd.y; hid[14]=bd.z; hid[15]=bd.w;
            }
            #pragma unroll
            for (int i = 0; i < 16; ++i) {
                const float xi = x[i];
                const float4 wa = *(const float4*)&Wl[i * 16];
                const float4 wb = *(const float4*)&Wl[i * 16 + 4];
                const float4 wc = *(const float4*)&Wl[i * 16 + 8];
                const float4 wd = *(const float4*)&Wl[i * 16 + 12];
                hid[0]  += xi * wa.x; hid[1]  += xi * wa.y; hid[2]  += xi * wa.z; hid[3]  += xi * wa.w;
                hid[4]  += xi * wb.x; hid[5]  += xi * wb.y; hid[6]  += xi * wb.z; hid[7]  += xi * wb.w;
                hid[8]  += xi * wc.x; hid[9]  += xi * wc.y; hid[10] += xi * wc.z; hid[11] += xi * wc.w;
                hid[12] += xi * wd.x; hid[13] += xi * wd.y; hid[14] += xi * wd.z; hid[15] += xi * wd.w;
            }
            float f[8];
            {
                const float4 c0 = *(const float4*)&Wl[400];
                const float4 c1 = *(const float4*)&Wl[404];
                f[0]=c0.x; f[1]=c0.y; f[2]=c0.z; f[3]=c0.w;
                f[4]=c1.x; f[5]=c1.y; f[6]=c1.z; f[7]=c1.w;
            }
            #pragma unroll
            for (int j = 0; j < 16; ++j) {
                const float hj = fmaxf(hid[j], 0.f);   // relu folded
                const float4 w0 = *(const float4*)&Wl[256 + j * 8];
                const float4 w1 = *(const float4*)&Wl[256 + j * 8 + 4];
                f[0] += hj * w0.x; f[1] += hj * w0.y; f[2] += hj * w0.z; f[3] += hj * w0.w;
                f[4] += hj * w1.x; f[5] += hj * w1.y; f[6] += hj * w1.z; f[7] += hj * w1.w;
            }
            *(float4*)&Sx[mlp_n * 132 + mlp_m * 8]     = make_float4(f[0], f[1], f[2], f[3]);
            *(float4*)&Sx[mlp_n * 132 + mlp_m * 8 + 4] = make_float4(f[4], f[5], f[6], f[7]);
        }
        __syncthreads();

        // ---- online softmax reduce per (n, h) ----
        if (tid < 128) {
            int n = tid >> 3, h = tid & 7;
            float Mo = Mst[tid], Lo = Lst[tid];
            float mx = -INFINITY;
            #pragma unroll
            for (int mm = 0; mm < 16; ++mm) mx = fmaxf(mx, Sx[n * 132 + mm * 8 + h]);
            float nM = fmaxf(Mo, mx);
            float al = __expf(Mo - nM);
            float sm = 0.f;
            #pragma unroll
            for (int mm = 0; mm < 16; ++mm) {
                float pp = __expf(Sx[n * 132 + mm * 8 + h] - nM);
                Sx[n * 132 + mm * 8 + h] = pp;
                sm += pp;
            }
            Mst[tid] = nM; Lst[tid] = Lo * al + sm; Alph[tid] = al;
        }
        __syncthreads();

        // ---- A @ V, rescaled accumulator ----
        {
            const float al = Alph[sn * 8 + sh];
            #pragma unroll
            for (int i = 0; i < 16; ++i) acc[i] *= al;
            #pragma unroll
            for (int mm = 0; mm < 16; ++mm) {
                const float pm = Sx[sn * 132 + mm * 8 + sh];
                const float* vr = &Vs[(mm * 8 + sh) * 36 + smh * 16];
                #pragma unroll
                for (int j4 = 0; j4 < 4; ++j4) {
                    float4 v = *(const float4*)(vr + j4 * 4);
                    acc[j4*4+0] += pm * v.x; acc[j4*4+1] += pm * v.y;
                    acc[j4*4+2] += pm * v.z; acc[j4*4+3] += pm * v.w;
                }
            }
        }
        __syncthreads();
    }

    // ---- epilogue: normalize, (optionally accumulate) into heads[b][q][h*32+e] ----
    {
        const float inv = 1.f / Lst[sn * 8 + sh];
        const int q = q_off + n0g + sn;
        float* dst = heads + ((size_t)b * 512 + q) * 256 + sh * 32 + smh * 16;
        if (accum) {
            #pragma unroll
            for (int j4 = 0; j4 < 4; ++j4) {
                float4 o = *(const float4*)(dst + j4 * 4);
                o.x += acc[j4*4+0] * inv; o.y += acc[j4*4+1] * inv;
                o.z += acc[j4*4+2] * inv; o.w += acc[j4*4+3] * inv;
                *(float4*)(dst + j4 * 4) = o;
            }
        } else {
            #pragma unroll
            for (int j4 = 0; j4 < 4; ++j4) {
                *(float4*)(dst + j4 * 4) = make_float4(acc[j4*4+0] * inv, acc[j4*4+1] * inv,
                                                       acc[j4*4+2] * inv, acc[j4*4+3] * inv);
            }
        }
    }
}

// ---------------------------------------------------------------------------
extern "C" void kernel_launch(void* const* d_in, const int* in_sizes, int n_in,
                              void* d_out, int out_size, void* d_ws, size_t ws_size,
                              hipStream_t stream)
{
    (void)in_sizes; (void)n_in; (void)out_size; (void)ws_size;

    const float* h_fea  = (const float*)d_in[0];
    const float* aux    = (const float*)d_in[1];
    const float* Wq_c   = (const float*)d_in[2];   // Wq_custom
    const float* Wq_c1  = (const float*)d_in[3];   // Wq_custom1
    const float* Wk_c   = (const float*)d_in[4];   // Wk_custom
    const float* Wv_c   = (const float*)d_in[5];   // Wv_custom
    const float* Wq_ch1 = (const float*)d_in[6];   // Wq_charge1
    const float* Wk_ch  = (const float*)d_in[7];   // Wk_charge
    const float* Wv_ch  = (const float*)d_in[8];   // Wv_charge
    const float* W1     = (const float*)d_in[9];
    const float* b1     = (const float*)d_in[10];
    const float* W2     = (const float*)d_in[11];
    const float* b2     = (const float*)d_in[12];
    const float* W_out  = (const float*)d_in[13];

    float* ws  = (float*)d_ws;
    const size_t TBIG = 8u * 16u * 448u * 32u;   // 1,835,008
    const size_t TSML = 8u * 16u * 64u * 32u;    //   262,144
    float* QT1 = ws;
    float* QT  = ws + TBIG;
    float* KC  = ws + 2 * TBIG;
    float* VC  = ws + 3 * TBIG;
    float* QS  = ws + 4 * TBIG;
    float* KS  = QS + TSML;
    float* VS  = KS + TSML;
    float* HE  = VS + TSML;                      // 16*512*256 floats

    // Projections: task rows (q 64..511) and station rows (q 0..63)
    proj_gemm<<<dim3(112, 16), 256, 0, stream>>>(h_fea, Wq_c1, Wq_c, Wk_c, Wv_c,
                                                 QT1, QT, KC, VC, 64, 448, 7);
    proj_gemm<<<dim3(16, 12), 256, 0, stream>>>(h_fea, Wq_ch1, Wk_ch, Wv_ch, Wv_ch,
                                                QS, KS, VS, VS, 0, 64, 1);

    // heads_targe = attend(Qt1, K_c, aux[:,:,64:,64:], V_c)
    attend_kernel<<<dim3(28, 16), 256, 0, stream>>>(QT1, KC, VC, aux, W1, b1, W2, b2,
                                                    HE, 448, 448, 64, 64, 64, 0);
    //             + attend(Qt, K_s, aux[:,:,64:,:64], V_s)   (accumulate)
    attend_kernel<<<dim3(28, 16), 256, 0, stream>>>(QT, KS, VS, aux, W1, b1, W2, b2,
                                                    HE, 448, 64, 64, 0, 64, 1);
    // heads_station = attend(Qs, K_c, aux[:,:,:64,64:], V_c)
    attend_kernel<<<dim3(4, 16), 256, 0, stream>>>(QS, KC, VC, aux, W1, b1, W2, b2,
                                                   HE, 64, 448, 0, 64, 0, 0);

    // h_wave = einsum('hbqe,hed->bqd') == HEADS[8192,256] @ W_out[256,256]
    out_gemm<<<dim3(128, 4), 256, 0, stream>>>(HE, W_out, (float*)d_out);
}

// Round 2
// 764.065 us; speedup vs baseline: 1.2873x; 1.2873x over previous
//
#include <hip/hip_runtime.h>
#include <math.h>

// Shapes (fixed): H=8, D=256, HD=32, B=16, Q=512, S1=64, NTASK=448

// ---------------------------------------------------------------------------
// Projection GEMM: out_p[h][b][n][e] = sum_d h_fea[b, q_off+n, d] * Wp[h, d, e]
// ---------------------------------------------------------------------------
__global__ __launch_bounds__(256)
void proj_gemm(const float* __restrict__ A,
               const float* __restrict__ W0, const float* __restrict__ W1p,
               const float* __restrict__ W2p, const float* __restrict__ W3p,
               float* __restrict__ O0, float* __restrict__ O1,
               float* __restrict__ O2, float* __restrict__ O3,
               int q_off, int rows_per_b, int tiles_per_b)
{
    __shared__ float Asub[32][68];
    __shared__ float Bsub[32][68];
    const int tid = (int)threadIdx.x;
    const int b  = (int)blockIdx.x / tiles_per_b;
    const int n0 = ((int)blockIdx.x % tiles_per_b) * 64;
    const int p  = (int)blockIdx.y >> 2;
    const int cb = ((int)blockIdx.y & 3) * 64;
    const float* Wp = (p == 0) ? W0 : (p == 1) ? W1p : (p == 2) ? W2p : W3p;
    float* Op       = (p == 0) ? O0 : (p == 1) ? O1 : (p == 2) ? O2 : O3;

    const int tx = tid & 15, ty = tid >> 4;
    float acc[4][4] = {};
    const float* Arow = A + (size_t)(b * 512 + q_off + n0) * 256;

    for (int k0 = 0; k0 < 256; k0 += 32) {
        #pragma unroll
        for (int i = 0; i < 8; ++i) {
            int idx = tid + 256 * i;
            int kk = idx & 31, r = idx >> 5;
            Asub[kk][r] = Arow[(size_t)r * 256 + k0 + kk];
        }
        #pragma unroll
        for (int i = 0; i < 8; ++i) {
            int idx = tid + 256 * i;
            int c = idx & 63, kk = idx >> 6;
            int cg = cb + c;
            int h = cg >> 5, e = cg & 31;
            Bsub[kk][c] = Wp[(size_t)(h * 256 + k0 + kk) * 32 + e];
        }
        __syncthreads();
        #pragma unroll
        for (int kk = 0; kk < 32; ++kk) {
            float4 a4 = *(const float4*)&Asub[kk][ty * 4];
            float4 b4 = *(const float4*)&Bsub[kk][tx * 4];
            acc[0][0] += a4.x * b4.x; acc[0][1] += a4.x * b4.y; acc[0][2] += a4.x * b4.z; acc[0][3] += a4.x * b4.w;
            acc[1][0] += a4.y * b4.x; acc[1][1] += a4.y * b4.y; acc[1][2] += a4.y * b4.z; acc[1][3] += a4.y * b4.w;
            acc[2][0] += a4.z * b4.x; acc[2][1] += a4.z * b4.y; acc[2][2] += a4.z * b4.z; acc[2][3] += a4.z * b4.w;
            acc[3][0] += a4.w * b4.x; acc[3][1] += a4.w * b4.y; acc[3][2] += a4.w * b4.z; acc[3][3] += a4.w * b4.w;
        }
        __syncthreads();
    }
    const int cg = cb + tx * 4;
    const int h = cg >> 5, e = cg & 31;
    #pragma unroll
    for (int i = 0; i < 4; ++i) {
        int n = n0 + ty * 4 + i;
        float4 v = make_float4(acc[i][0], acc[i][1], acc[i][2], acc[i][3]);
        *(float4*)&Op[(((size_t)h * 16 + b) * rows_per_b + n) * 32 + e] = v;
    }
}

// ---------------------------------------------------------------------------
// Output projection: C[bq][d] = HEADS[8192,256] @ W_out[256,256]
// ---------------------------------------------------------------------------
__global__ __launch_bounds__(256)
void out_gemm(const float* __restrict__ A, const float* __restrict__ Bm,
              float* __restrict__ C)
{
    __shared__ float Asub[32][68];
    __shared__ float Bsub[32][68];
    const int tid = (int)threadIdx.x;
    const int row0 = (int)blockIdx.x * 64;
    const int col0 = (int)blockIdx.y * 64;
    const int tx = tid & 15, ty = tid >> 4;
    float acc[4][4] = {};

    for (int k0 = 0; k0 < 256; k0 += 32) {
        #pragma unroll
        for (int i = 0; i < 8; ++i) {
            int idx = tid + 256 * i;
            int kk = idx & 31, r = idx >> 5;
            Asub[kk][r] = A[(size_t)(row0 + r) * 256 + k0 + kk];
        }
        #pragma unroll
        for (int i = 0; i < 8; ++i) {
            int idx = tid + 256 * i;
            int c = idx & 63, kk = idx >> 6;
            Bsub[kk][c] = Bm[(size_t)(k0 + kk) * 256 + col0 + c];
        }
        __syncthreads();
        #pragma unroll
        for (int kk = 0; kk < 32; ++kk) {
            float4 a4 = *(const float4*)&Asub[kk][ty * 4];
            float4 b4 = *(const float4*)&Bsub[kk][tx * 4];
            acc[0][0] += a4.x * b4.x; acc[0][1] += a4.x * b4.y; acc[0][2] += a4.x * b4.z; acc[0][3] += a4.x * b4.w;
            acc[1][0] += a4.y * b4.x; acc[1][1] += a4.y * b4.y; acc[1][2] += a4.y * b4.z; acc[1][3] += a4.y * b4.w;
            acc[2][0] += a4.z * b4.x; acc[2][1] += a4.z * b4.y; acc[2][2] += a4.z * b4.z; acc[2][3] += a4.z * b4.w;
            acc[3][0] += a4.w * b4.x; acc[3][1] += a4.w * b4.y; acc[3][2] += a4.w * b4.z; acc[3][3] += a4.w * b4.w;
        }
        __syncthreads();
    }
    #pragma unroll
    for (int i = 0; i < 4; ++i) {
        float4 v = make_float4(acc[i][0], acc[i][1], acc[i][2], acc[i][3]);
        *(float4*)&C[(size_t)(row0 + ty * 4 + i) * 256 + col0 + tx * 4] = v;
    }
}

// ---------------------------------------------------------------------------
// Key-split attend partial: scores -> fuse-MLP+online-softmax (shfl) -> A@V
// Writes UNNORMALIZED o (32 floats per (chunk,h,b,n)) and (m,l) per row.
// grid: (NR/16, B, ML/KCHUNK). block 256.
// ---------------------------------------------------------------------------
__global__ __launch_bounds__(256)
void attend_part(const float* __restrict__ Qb, const float* __restrict__ Kb,
                 const float* __restrict__ Vb, const float* __restrict__ aux,
                 const float* __restrict__ W1g, const float* __restrict__ b1g,
                 const float* __restrict__ W2g, const float* __restrict__ b2g,
                 float* __restrict__ o_part, float* __restrict__ ml_part,
                 int NR, int ML, int KCHUNK, int n_off, int m_off)
{
    __shared__ float Ks[128 * 36];     // [mm*8+h][36]
    __shared__ float Vs[128 * 36];
    __shared__ float Sx[16 * 226];     // [n]*226 + m*14 + h
    __shared__ float Wl[408];          // W1(256) | W2(128) | b1(16) | b2(8)
    __shared__ float Alph[128];

    const int tid   = (int)threadIdx.x;
    const int n0g   = (int)blockIdx.x * 16;
    const int b     = (int)blockIdx.y;
    const int chunk = (int)blockIdx.z;
    const int m_base = chunk * KCHUNK;

    Wl[tid] = W1g[tid];
    if (tid < 128) Wl[256 + tid] = W2g[tid];
    if (tid < 16)  Wl[384 + tid] = b1g[tid];
    if (tid < 8)   Wl[400 + tid] = b2g[tid];

    // score/AV mapping
    const int sn  = tid >> 4;
    const int sh  = (tid >> 1) & 7;
    const int smh = tid & 1;
    // MLP mapping (note sn == mn)
    const int mn  = tid >> 4;
    const int mm_ = tid & 15;

    float qreg[32];
    {
        const float* qsrc = Qb + (((size_t)sh * 16 + b) * NR + n0g + sn) * 32;
        #pragma unroll
        for (int i = 0; i < 8; ++i) {
            float4 t = *(const float4*)(qsrc + i * 4);
            qreg[i*4+0] = t.x; qreg[i*4+1] = t.y; qreg[i*4+2] = t.z; qreg[i*4+3] = t.w;
        }
    }

    float acc[16];
    #pragma unroll
    for (int i = 0; i < 16; ++i) acc[i] = 0.f;
    float Mreg[8], Lreg[8];
    #pragma unroll
    for (int h = 0; h < 8; ++h) { Mreg[h] = -INFINITY; Lreg[h] = 0.f; }

    float auxr[8];
    float* sx_mlp = &Sx[mn * 226 + mm_ * 14];
    __syncthreads();

    for (int m0 = m_base; m0 < m_base + KCHUNK; m0 += 16) {
        // ---- stage K/V; prefetch aux for this step's MLP ----
        {
            int row = tid >> 1, half = tid & 1;
            int mm = row >> 3, h = row & 7;
            const float* ksrc = Kb + (((size_t)h * 16 + b) * ML + m0 + mm) * 32 + half * 16;
            const float* vsrc = Vb + (((size_t)h * 16 + b) * ML + m0 + mm) * 32 + half * 16;
            float4 kr[4], vr[4];
            #pragma unroll
            for (int i = 0; i < 4; ++i) kr[i] = *(const float4*)(ksrc + i * 4);
            #pragma unroll
            for (int i = 0; i < 4; ++i) vr[i] = *(const float4*)(vsrc + i * 4);
            // aux prefetch (consumed 2 barriers later in the MLP phase)
            #pragma unroll
            for (int h2 = 0; h2 < 8; ++h2)
                auxr[h2] = aux[(((size_t)h2 * 16 + b) * 512 + (n_off + n0g + mn)) * 512
                               + (m_off + m0 + mm_)];
            float* kd = &Ks[(mm * 8 + h) * 36 + half * 16];
            float* vd = &Vs[(mm * 8 + h) * 36 + half * 16];
            #pragma unroll
            for (int i = 0; i < 4; ++i) *(float4*)(kd + i * 4) = kr[i];
            #pragma unroll
            for (int i = 0; i < 4; ++i) *(float4*)(vd + i * 4) = vr[i];
        }
        __syncthreads();

        // ---- scores: s[n, m, h] = Q[n,h] . K[m,h] ----
        #pragma unroll
        for (int mm8 = 0; mm8 < 8; ++mm8) {
            int mm = smh * 8 + mm8;
            const float* kr = &Ks[(mm * 8 + sh) * 36];
            float s = 0.f;
            #pragma unroll
            for (int i = 0; i < 8; ++i) {
                float4 kv = *(const float4*)(kr + i * 4);
                s += qreg[i*4+0] * kv.x + qreg[i*4+1] * kv.y
                   + qreg[i*4+2] * kv.z + qreg[i*4+3] * kv.w;
            }
            Sx[sn * 226 + mm * 14 + sh] = s;
        }
        __syncthreads();

        // ---- fuse MLP + online softmax (shfl over the 16 m-lanes) ----
        {
            float x[16];
            #pragma unroll
            for (int h = 0; h < 8; ++h) x[h] = sx_mlp[h];
            #pragma unroll
            for (int h = 0; h < 8; ++h) x[8 + h] = auxr[h];
            float hid[16];
            #pragma unroll
            for (int j = 0; j < 16; ++j) hid[j] = Wl[384 + j];
            #pragma unroll
            for (int i = 0; i < 16; ++i) {
                const float xi = x[i];
                #pragma unroll
                for (int j = 0; j < 16; ++j) hid[j] += xi * Wl[i * 16 + j];
            }
            float f[8];
            #pragma unroll
            for (int o = 0; o < 8; ++o) f[o] = Wl[400 + o];
            #pragma unroll
            for (int j = 0; j < 16; ++j) {
                const float hj = fmaxf(hid[j], 0.f);
                #pragma unroll
                for (int o = 0; o < 8; ++o) f[o] += hj * Wl[256 + j * 8 + o];
            }
            // row max across the 16 m-lanes
            float rmax[8];
            #pragma unroll
            for (int h = 0; h < 8; ++h) rmax[h] = f[h];
            #pragma unroll
            for (int d = 1; d < 16; d <<= 1) {
                #pragma unroll
                for (int h = 0; h < 8; ++h)
                    rmax[h] = fmaxf(rmax[h], __shfl_xor(rmax[h], d));
            }
            float p[8], rsum[8], alr[8];
            #pragma unroll
            for (int h = 0; h < 8; ++h) {
                float nM = fmaxf(Mreg[h], rmax[h]);
                alr[h] = __expf(Mreg[h] - nM);
                p[h] = __expf(f[h] - nM);
                rsum[h] = p[h];
                Mreg[h] = nM;
            }
            #pragma unroll
            for (int d = 1; d < 16; d <<= 1) {
                #pragma unroll
                for (int h = 0; h < 8; ++h)
                    rsum[h] += __shfl_xor(rsum[h], d);
            }
            #pragma unroll
            for (int h = 0; h < 8; ++h) {
                Lreg[h] = Lreg[h] * alr[h] + rsum[h];
                sx_mlp[h] = p[h];
            }
            if (mm_ == 0) {
                #pragma unroll
                for (int h = 0; h < 8; ++h) Alph[mn * 8 + h] = alr[h];
            }
        }
        __syncthreads();

        // ---- A @ V, rescaled accumulator ----
        {
            const float al = Alph[sn * 8 + sh];
            #pragma unroll
            for (int i = 0; i < 16; ++i) acc[i] *= al;
            #pragma unroll
            for (int mm = 0; mm < 16; ++mm) {
                const float pm = Sx[sn * 226 + mm * 14 + sh];
                const float* vr = &Vs[(mm * 8 + sh) * 36 + smh * 16];
                #pragma unroll
                for (int j4 = 0; j4 < 4; ++j4) {
                    float4 v = *(const float4*)(vr + j4 * 4);
                    acc[j4*4+0] += pm * v.x; acc[j4*4+1] += pm * v.y;
                    acc[j4*4+2] += pm * v.z; acc[j4*4+3] += pm * v.w;
                }
            }
        }
        __syncthreads();
    }

    // ---- epilogue: unnormalized o (AV threads), (m,l) (MLP lane 0 threads) ----
    {
        float* dst = o_part + ((((size_t)chunk * 8 + sh) * 16 + b) * NR + (n0g + sn)) * 32 + smh * 16;
        #pragma unroll
        for (int j4 = 0; j4 < 4; ++j4)
            *(float4*)(dst + j4 * 4) = make_float4(acc[j4*4+0], acc[j4*4+1], acc[j4*4+2], acc[j4*4+3]);
    }
    if (mm_ == 0) {
        #pragma unroll
        for (int h = 0; h < 8; ++h) {
            size_t base = ((((size_t)chunk * 8 + h) * 16 + b) * NR + (n0g + mn)) * 2;
            ml_part[base]     = Mreg[h];
            ml_part[base + 1] = Lreg[h];
        }
    }
}

// ---------------------------------------------------------------------------
// Combine: merge nchA key-chunks (shared softmax) + optional group-B partial
// (independent softmax, added). Writes heads layout HE[b][q_off+n][h*32+e].
// grid: (NR/16, B), block 256.
// ---------------------------------------------------------------------------
__global__ __launch_bounds__(256)
void combine_kernel(const float* __restrict__ oA, const float* __restrict__ mlA, int nchA,
                    const float* __restrict__ oB, const float* __restrict__ mlB,
                    float* __restrict__ HE, int NR, int q_off)
{
    const int tid = (int)threadIdx.x;
    const int sn = tid >> 4, sh = (tid >> 1) & 7, smh = tid & 1;
    const int n = (int)blockIdx.x * 16 + sn;
    const int b = (int)blockIdx.y;

    float M = -INFINITY;
    for (int c = 0; c < nchA; ++c)
        M = fmaxf(M, mlA[((((size_t)c * 8 + sh) * 16 + b) * NR + n) * 2]);
    float L = 0.f;
    float o[16];
    #pragma unroll
    for (int j = 0; j < 16; ++j) o[j] = 0.f;
    for (int c = 0; c < nchA; ++c) {
        size_t mlb = ((((size_t)c * 8 + sh) * 16 + b) * NR + n) * 2;
        float mc = mlA[mlb], lc = mlA[mlb + 1];
        float w = __expf(mc - M);
        L += lc * w;
        const float* src = oA + ((((size_t)c * 8 + sh) * 16 + b) * NR + n) * 32 + smh * 16;
        #pragma unroll
        for (int j4 = 0; j4 < 4; ++j4) {
            float4 v = *(const float4*)(src + j4 * 4);
            o[j4*4+0] += w * v.x; o[j4*4+1] += w * v.y;
            o[j4*4+2] += w * v.z; o[j4*4+3] += w * v.w;
        }
    }
    const float invL = 1.f / L;
    #pragma unroll
    for (int j = 0; j < 16; ++j) o[j] *= invL;

    if (oB != nullptr) {
        float lB = mlB[(((size_t)sh * 16 + b) * NR + n) * 2 + 1];
        const float invB = 1.f / lB;
        const float* src = oB + (((size_t)sh * 16 + b) * NR + n) * 32 + smh * 16;
        #pragma unroll
        for (int j4 = 0; j4 < 4; ++j4) {
            float4 v = *(const float4*)(src + j4 * 4);
            o[j4*4+0] += invB * v.x; o[j4*4+1] += invB * v.y;
            o[j4*4+2] += invB * v.z; o[j4*4+3] += invB * v.w;
        }
    }
    float* dst = HE + ((size_t)b * 512 + q_off + n) * 256 + sh * 32 + smh * 16;
    #pragma unroll
    for (int j4 = 0; j4 < 4; ++j4)
        *(float4*)(dst + j4 * 4) = make_float4(o[j4*4+0], o[j4*4+1], o[j4*4+2], o[j4*4+3]);
}

// ---------------------------------------------------------------------------
extern "C" void kernel_launch(void* const* d_in, const int* in_sizes, int n_in,
                              void* d_out, int out_size, void* d_ws, size_t ws_size,
                              hipStream_t stream)
{
    (void)in_sizes; (void)n_in; (void)out_size; (void)ws_size;

    const float* h_fea  = (const float*)d_in[0];
    const float* aux    = (const float*)d_in[1];
    const float* Wq_c   = (const float*)d_in[2];
    const float* Wq_c1  = (const float*)d_in[3];
    const float* Wk_c   = (const float*)d_in[4];
    const float* Wv_c   = (const float*)d_in[5];
    const float* Wq_ch1 = (const float*)d_in[6];
    const float* Wk_ch  = (const float*)d_in[7];
    const float* Wv_ch  = (const float*)d_in[8];
    const float* W1     = (const float*)d_in[9];
    const float* b1     = (const float*)d_in[10];
    const float* W2     = (const float*)d_in[11];
    const float* b2     = (const float*)d_in[12];
    const float* W_out  = (const float*)d_in[13];

    float* ws = (float*)d_ws;
    const size_t TBIG = 8u * 16u * 448u * 32u;   // 1,835,008
    const size_t TSML = 8u * 16u * 64u * 32u;    //   262,144
    size_t off = 0;
    float* QT1 = ws + off; off += TBIG;
    float* QT  = ws + off; off += TBIG;
    float* KC  = ws + off; off += TBIG;
    float* VC  = ws + off; off += TBIG;
    float* QS  = ws + off; off += TSML;
    float* KS  = ws + off; off += TSML;
    float* VS  = ws + off; off += TSML;
    float* HE  = ws + off; off += (size_t)16 * 512 * 256;
    float* oA  = ws + off; off += 4 * TBIG;                    // 4 chunks, task q
    float* mlA = ws + off; off += 4u * 8 * 16 * 448 * 2;
    float* oB  = ws + off; off += TBIG;                        // 1 chunk
    float* mlB = ws + off; off += 8u * 16 * 448 * 2;
    float* oC  = ws + off; off += 7 * TSML;                    // 7 chunks, stat q
    float* mlC = ws + off; off += 7u * 8 * 16 * 64 * 2;

    // Projections
    proj_gemm<<<dim3(112, 16), 256, 0, stream>>>(h_fea, Wq_c1, Wq_c, Wk_c, Wv_c,
                                                 QT1, QT, KC, VC, 64, 448, 7);
    proj_gemm<<<dim3(16, 12), 256, 0, stream>>>(h_fea, Wq_ch1, Wk_ch, Wv_ch, Wv_ch,
                                                QS, KS, VS, VS, 0, 64, 1);

    // attend1: task q vs task k (448 keys, 4 chunks of 112)
    attend_part<<<dim3(28, 16, 4), 256, 0, stream>>>(QT1, KC, VC, aux, W1, b1, W2, b2,
                                                     oA, mlA, 448, 448, 112, 64, 64);
    // attend2: task q vs stat k (64 keys, 1 chunk)
    attend_part<<<dim3(28, 16, 1), 256, 0, stream>>>(QT, KS, VS, aux, W1, b1, W2, b2,
                                                     oB, mlB, 448, 64, 64, 64, 0);
    // attend3: stat q vs task k (448 keys, 7 chunks of 64)
    attend_part<<<dim3(4, 16, 7), 256, 0, stream>>>(QS, KC, VC, aux, W1, b1, W2, b2,
                                                    oC, mlC, 64, 448, 64, 0, 64);

    // Combine: task rows = merge(A chunks) + normalize(B); stat rows = merge(C)
    combine_kernel<<<dim3(28, 16), 256, 0, stream>>>(oA, mlA, 4, oB, mlB, HE, 448, 64);
    combine_kernel<<<dim3(4, 16), 256, 0, stream>>>(oC, mlC, 7, nullptr, nullptr, HE, 64, 0);

    // h_wave = HEADS[8192,256] @ W_out[256,256]
    out_gemm<<<dim3(128, 4), 256, 0, stream>>>(HE, W_out, (float*)d_out);
}

// Round 3
// 583.410 us; speedup vs baseline: 1.6860x; 1.3097x over previous
//
#include <hip/hip_runtime.h>
#include <math.h>

// Shapes (fixed): H=8, D=256, HD=32, B=16, Q=512, S1=64, NTASK=448
typedef _Float16 f16;
typedef f16  f16x8 __attribute__((ext_vector_type(8)));
typedef f16  f16x4 __attribute__((ext_vector_type(4)));
typedef float f32x4 __attribute__((ext_vector_type(4)));

// ---------------------------------------------------------------------------
// Projection GEMM (fp32 compute, fp16 output).
// Normal outputs: [h][b][n][32] fp16 row-major.  V output (p==vt_p): V^T
// layout [h][b][e][NR] fp16 (contiguous m) for MFMA B-fragments.
// ---------------------------------------------------------------------------
__global__ __launch_bounds__(256)
void proj_gemm(const float* __restrict__ A,
               const float* __restrict__ W0, const float* __restrict__ W1p,
               const float* __restrict__ W2p, const float* __restrict__ W3p,
               f16* __restrict__ O0, f16* __restrict__ O1,
               f16* __restrict__ O2, f16* __restrict__ O3,
               int q_off, int rows_per_b, int tiles_per_b, int vt_p)
{
    __shared__ float Asub[32][68];
    __shared__ float Bsub[32][68];
    const int tid = (int)threadIdx.x;
    const int b  = (int)blockIdx.x / tiles_per_b;
    const int n0 = ((int)blockIdx.x % tiles_per_b) * 64;
    const int p  = (int)blockIdx.y >> 2;
    const int cb = ((int)blockIdx.y & 3) * 64;
    const float* Wp = (p == 0) ? W0 : (p == 1) ? W1p : (p == 2) ? W2p : W3p;
    f16* Op         = (p == 0) ? O0 : (p == 1) ? O1 : (p == 2) ? O2 : O3;

    const int tx = tid & 15, ty = tid >> 4;
    float acc[4][4] = {};
    const float* Arow = A + (size_t)(b * 512 + q_off + n0) * 256;

    for (int k0 = 0; k0 < 256; k0 += 32) {
        #pragma unroll
        for (int i = 0; i < 8; ++i) {
            int idx = tid + 256 * i;
            int kk = idx & 31, r = idx >> 5;
            Asub[kk][r] = Arow[(size_t)r * 256 + k0 + kk];
        }
        #pragma unroll
        for (int i = 0; i < 8; ++i) {
            int idx = tid + 256 * i;
            int c = idx & 63, kk = idx >> 6;
            int cg = cb + c;
            int h = cg >> 5, e = cg & 31;
            Bsub[kk][c] = Wp[(size_t)(h * 256 + k0 + kk) * 32 + e];
        }
        __syncthreads();
        #pragma unroll
        for (int kk = 0; kk < 32; ++kk) {
            float4 a4 = *(const float4*)&Asub[kk][ty * 4];
            float4 b4 = *(const float4*)&Bsub[kk][tx * 4];
            acc[0][0] += a4.x * b4.x; acc[0][1] += a4.x * b4.y; acc[0][2] += a4.x * b4.z; acc[0][3] += a4.x * b4.w;
            acc[1][0] += a4.y * b4.x; acc[1][1] += a4.y * b4.y; acc[1][2] += a4.y * b4.z; acc[1][3] += a4.y * b4.w;
            acc[2][0] += a4.z * b4.x; acc[2][1] += a4.z * b4.y; acc[2][2] += a4.z * b4.z; acc[2][3] += a4.z * b4.w;
            acc[3][0] += a4.w * b4.x; acc[3][1] += a4.w * b4.y; acc[3][2] += a4.w * b4.z; acc[3][3] += a4.w * b4.w;
        }
        __syncthreads();
    }
    const int cg = cb + tx * 4;
    const int h = cg >> 5, e = cg & 31;
    if (p == vt_p) {
        // V^T: Op[((h*16+b)*32 + e+j)*NR + n]
        #pragma unroll
        for (int i = 0; i < 4; ++i) {
            int n = n0 + ty * 4 + i;
            #pragma unroll
            for (int j = 0; j < 4; ++j)
                Op[(((size_t)h * 16 + b) * 32 + e + j) * rows_per_b + n] = (f16)acc[i][j];
        }
    } else {
        #pragma unroll
        for (int i = 0; i < 4; ++i) {
            int n = n0 + ty * 4 + i;
            f16x4 v = { (f16)acc[i][0], (f16)acc[i][1], (f16)acc[i][2], (f16)acc[i][3] };
            *(f16x4*)&Op[(((size_t)h * 16 + b) * rows_per_b + n) * 32 + e] = v;
        }
    }
}

// ---------------------------------------------------------------------------
// Output projection: C[bq][d] = HEADS[8192,256] @ W_out[256,256]  (fp32)
// ---------------------------------------------------------------------------
__global__ __launch_bounds__(256)
void out_gemm(const float* __restrict__ A, const float* __restrict__ Bm,
              float* __restrict__ C)
{
    __shared__ float Asub[32][68];
    __shared__ float Bsub[32][68];
    const int tid = (int)threadIdx.x;
    const int row0 = (int)blockIdx.x * 64;
    const int col0 = (int)blockIdx.y * 64;
    const int tx = tid & 15, ty = tid >> 4;
    float acc[4][4] = {};

    for (int k0 = 0; k0 < 256; k0 += 32) {
        #pragma unroll
        for (int i = 0; i < 8; ++i) {
            int idx = tid + 256 * i;
            int kk = idx & 31, r = idx >> 5;
            Asub[kk][r] = A[(size_t)(row0 + r) * 256 + k0 + kk];
        }
        #pragma unroll
        for (int i = 0; i < 8; ++i) {
            int idx = tid + 256 * i;
            int c = idx & 63, kk = idx >> 6;
            Bsub[kk][c] = Bm[(size_t)(k0 + kk) * 256 + col0 + c];
        }
        __syncthreads();
        #pragma unroll
        for (int kk = 0; kk < 32; ++kk) {
            float4 a4 = *(const float4*)&Asub[kk][ty * 4];
            float4 b4 = *(const float4*)&Bsub[kk][tx * 4];
            acc[0][0] += a4.x * b4.x; acc[0][1] += a4.x * b4.y; acc[0][2] += a4.x * b4.z; acc[0][3] += a4.x * b4.w;
            acc[1][0] += a4.y * b4.x; acc[1][1] += a4.y * b4.y; acc[1][2] += a4.y * b4.z; acc[1][3] += a4.y * b4.w;
            acc[2][0] += a4.z * b4.x; acc[2][1] += a4.z * b4.y; acc[2][2] += a4.z * b4.z; acc[2][3] += a4.z * b4.w;
            acc[3][0] += a4.w * b4.x; acc[3][1] += a4.w * b4.y; acc[3][2] += a4.w * b4.z; acc[3][3] += a4.w * b4.w;
        }
        __syncthreads();
    }
    #pragma unroll
    for (int i = 0; i < 4; ++i) {
        float4 v = make_float4(acc[i][0], acc[i][1], acc[i][2], acc[i][3]);
        *(float4*)&C[(size_t)(row0 + ty * 4 + i) * 256 + col0 + tx * 4] = v;
    }
}

// ---------------------------------------------------------------------------
// MFMA attend partial. 16 query rows x 32 keys per step, all 8 heads.
// Wave w owns heads 2w, 2w+1.  K: [h][b][m][32] f16.  V^T: [h][b][e][ML] f16.
// Scores via mfma 16x16x32 (HD=32=K); P@V via mfma 16x16x32 (Mstep=32=K).
// MLP/softmax in fp32 VALU.  Writes unnormalized o (f16) + (m,l) per row.
// ---------------------------------------------------------------------------
__global__ __launch_bounds__(256)
void attend_mfma(const f16* __restrict__ Qb, const f16* __restrict__ Kb,
                 const f16* __restrict__ Vt, const float* __restrict__ aux,
                 const float* __restrict__ W1g, const float* __restrict__ b1g,
                 const float* __restrict__ W2g, const float* __restrict__ b2g,
                 f16* __restrict__ o_part, float* __restrict__ ml_part,
                 int NR, int ML, int KCHUNK, int n_off, int m_off)
{
    __shared__ float Sx[16 * 289];       // [n]*289 + m*9 + h   (m 0..31, h 0..7)
    __shared__ f16   Pb[8 * 16 * 32];    // [h][n][m] f16 (A-frag friendly)
    __shared__ float Wl[408];            // W1(256) | W2(128) | b1(16) | b2(8)
    __shared__ float Alph[128];          // [n][h]

    const int tid   = (int)threadIdx.x;
    const int n0g   = (int)blockIdx.x * 16;
    const int b     = (int)blockIdx.y;
    const int chunk = (int)blockIdx.z;
    const int m_base = chunk * KCHUNK;

    Wl[tid] = W1g[tid];
    if (tid < 128) Wl[256 + tid] = W2g[tid];
    if (tid < 16)  Wl[384 + tid] = b1g[tid];
    if (tid < 8)   Wl[400 + tid] = b2g[tid];

    const int lane = tid & 63, ln = lane & 15, qd = lane >> 4;
    const int wid  = tid >> 6;
    const int h0   = wid * 2;
    // MLP role
    const int mn = tid >> 4, mi = tid & 15;

    // Q fragments (A-layout: row=ln, k=qd*8..qd*8+7), resident all steps
    f16x8 qf[2];
    #pragma unroll
    for (int t = 0; t < 2; ++t)
        qf[t] = *(const f16x8*)(Qb + ((((size_t)(h0 + t) * 16 + b) * NR + n0g + ln) * 32) + qd * 8);

    f32x4 oacc[2][2];
    #pragma unroll
    for (int t = 0; t < 2; ++t)
        #pragma unroll
        for (int hf = 0; hf < 2; ++hf)
            oacc[t][hf] = (f32x4){0.f, 0.f, 0.f, 0.f};

    float Mreg[8], Lreg[8];
    #pragma unroll
    for (int h = 0; h < 8; ++h) { Mreg[h] = -INFINITY; Lreg[h] = 0.f; }

    // aux prefetch for first step (MLP role: row n0g+mn, cols m_off+m_base+mi{,+16})
    const size_t aux_row = ((size_t)b * 512 + (n_off + n0g + mn)) * 512 + m_off;
    float auxr[16];
    #pragma unroll
    for (int h = 0; h < 8; ++h) {
        auxr[h]     = aux[(size_t)h * 16 * 512 * 512 + aux_row + m_base + mi];
        auxr[8 + h] = aux[(size_t)h * 16 * 512 * 512 + aux_row + m_base + mi + 16];
    }
    __syncthreads();

    for (int m0 = m_base; m0 < m_base + KCHUNK; m0 += 32) {
        // ---- phase A: scores via MFMA, scatter C-frags to Sx ----
        #pragma unroll
        for (int t = 0; t < 2; ++t) {
            const int h = h0 + t;
            #pragma unroll
            for (int mt = 0; mt < 2; ++mt) {
                f16x8 kf = *(const f16x8*)(Kb + ((((size_t)h * 16 + b) * ML + m0 + mt * 16 + ln) * 32) + qd * 8);
                f32x4 c = __builtin_amdgcn_mfma_f32_16x16x32_f16(qf[t], kf, (f32x4){0.f,0.f,0.f,0.f}, 0, 0, 0);
                #pragma unroll
                for (int r = 0; r < 4; ++r)
                    Sx[(qd * 4 + r) * 289 + (mt * 16 + ln) * 9 + h] = c[r];
            }
        }
        __syncthreads();

        // ---- phase B: fuse MLP (2 positions/thread) + online softmax ----
        {
            float x0[16], x1[16];
            #pragma unroll
            for (int h = 0; h < 8; ++h) {
                x0[h] = Sx[mn * 289 + mi * 9 + h];
                x1[h] = Sx[mn * 289 + (mi + 16) * 9 + h];
                x0[8 + h] = auxr[h];
                x1[8 + h] = auxr[8 + h];
            }
            float hid0[16], hid1[16];
            #pragma unroll
            for (int j = 0; j < 16; ++j) { float bj = Wl[384 + j]; hid0[j] = bj; hid1[j] = bj; }
            #pragma unroll
            for (int i = 0; i < 16; ++i) {
                const float a0 = x0[i], a1 = x1[i];
                #pragma unroll
                for (int j = 0; j < 16; ++j) {
                    const float w = Wl[i * 16 + j];
                    hid0[j] += a0 * w; hid1[j] += a1 * w;
                }
            }
            float f0[8], f1[8];
            #pragma unroll
            for (int o = 0; o < 8; ++o) { float bo = Wl[400 + o]; f0[o] = bo; f1[o] = bo; }
            #pragma unroll
            for (int j = 0; j < 16; ++j) {
                const float g0 = fmaxf(hid0[j], 0.f), g1 = fmaxf(hid1[j], 0.f);
                #pragma unroll
                for (int o = 0; o < 8; ++o) {
                    const float w = Wl[256 + j * 8 + o];
                    f0[o] += g0 * w; f1[o] += g1 * w;
                }
            }
            // softmax over the 32 m (2 in-thread x 16 lanes)
            float rmax[8];
            #pragma unroll
            for (int h = 0; h < 8; ++h) rmax[h] = fmaxf(f0[h], f1[h]);
            #pragma unroll
            for (int d = 1; d < 16; d <<= 1)
                #pragma unroll
                for (int h = 0; h < 8; ++h) rmax[h] = fmaxf(rmax[h], __shfl_xor(rmax[h], d));
            float alr[8], rsum[8];
            #pragma unroll
            for (int h = 0; h < 8; ++h) {
                const float nM = fmaxf(Mreg[h], rmax[h]);
                alr[h] = __expf(Mreg[h] - nM);
                const float e0 = __expf(f0[h] - nM);
                const float e1 = __expf(f1[h] - nM);
                f0[h] = e0; f1[h] = e1;
                rsum[h] = e0 + e1;
                Mreg[h] = nM;
            }
            #pragma unroll
            for (int d = 1; d < 16; d <<= 1)
                #pragma unroll
                for (int h = 0; h < 8; ++h) rsum[h] += __shfl_xor(rsum[h], d);
            #pragma unroll
            for (int h = 0; h < 8; ++h) {
                Lreg[h] = Lreg[h] * alr[h] + rsum[h];
                Pb[((size_t)h * 16 + mn) * 32 + mi]      = (f16)f0[h];
                Pb[((size_t)h * 16 + mn) * 32 + mi + 16] = (f16)f1[h];
            }
            if (mi == 0) {
                #pragma unroll
                for (int h = 0; h < 8; ++h) Alph[mn * 8 + h] = alr[h];
            }
            // prefetch aux for next step (long distance: consumed after 2 barriers)
            if (m0 + 32 < m_base + KCHUNK) {
                #pragma unroll
                for (int h = 0; h < 8; ++h) {
                    auxr[h]     = aux[(size_t)h * 16 * 512 * 512 + aux_row + m0 + 32 + mi];
                    auxr[8 + h] = aux[(size_t)h * 16 * 512 * 512 + aux_row + m0 + 32 + mi + 16];
                }
            }
        }
        __syncthreads();

        // ---- phase C: rescale accumulators, P @ V via MFMA ----
        #pragma unroll
        for (int t = 0; t < 2; ++t) {
            const int h = h0 + t;
            float al[4];
            #pragma unroll
            for (int r = 0; r < 4; ++r) al[r] = Alph[(qd * 4 + r) * 8 + h];
            f16x8 pf = *(const f16x8*)&Pb[((size_t)h * 16 + ln) * 32 + qd * 8];
            #pragma unroll
            for (int hf = 0; hf < 2; ++hf) {
                f16x8 vf = *(const f16x8*)(Vt + ((((size_t)h * 16 + b) * 32 + hf * 16 + ln) * ML) + m0 + qd * 8);
                f32x4 c = oacc[t][hf];
                #pragma unroll
                for (int r = 0; r < 4; ++r) c[r] *= al[r];
                oacc[t][hf] = __builtin_amdgcn_mfma_f32_16x16x32_f16(pf, vf, c, 0, 0, 0);
            }
        }
    }

    // ---- epilogue: unnormalized o (f16), (m,l) fp32 ----
    #pragma unroll
    for (int t = 0; t < 2; ++t) {
        const int h = h0 + t;
        #pragma unroll
        for (int hf = 0; hf < 2; ++hf)
            #pragma unroll
            for (int r = 0; r < 4; ++r)
                o_part[(((((size_t)chunk * 8 + h) * 16 + b) * NR + n0g + qd * 4 + r) * 32) + hf * 16 + ln]
                    = (f16)oacc[t][hf][r];
    }
    if (mi == 0) {
        #pragma unroll
        for (int h = 0; h < 8; ++h) {
            const size_t base = ((((size_t)chunk * 8 + h) * 16 + b) * NR + n0g + mn) * 2;
            ml_part[base]     = Mreg[h];
            ml_part[base + 1] = Lreg[h];
        }
    }
}

// ---------------------------------------------------------------------------
// Combine: merge nchA key-chunks (shared softmax) + optional group-B partial
// (independent softmax, added). Writes HE[b][q_off+n][h*32+e] fp32.
// ---------------------------------------------------------------------------
__global__ __launch_bounds__(256)
void combine_kernel(const f16* __restrict__ oA, const float* __restrict__ mlA, int nchA,
                    const f16* __restrict__ oB, const float* __restrict__ mlB,
                    float* __restrict__ HE, int NR, int q_off)
{
    const int tid = (int)threadIdx.x;
    const int sn = tid >> 4, sh = (tid >> 1) & 7, smh = tid & 1;
    const int n = (int)blockIdx.x * 16 + sn;
    const int b = (int)blockIdx.y;

    float M = -INFINITY;
    for (int c = 0; c < nchA; ++c)
        M = fmaxf(M, mlA[((((size_t)c * 8 + sh) * 16 + b) * NR + n) * 2]);
    float L = 0.f;
    float o[16];
    #pragma unroll
    for (int j = 0; j < 16; ++j) o[j] = 0.f;
    for (int c = 0; c < nchA; ++c) {
        const size_t mlb = ((((size_t)c * 8 + sh) * 16 + b) * NR + n) * 2;
        const float w = __expf(mlA[mlb] - M);
        L += mlA[mlb + 1] * w;
        const f16* src = oA + ((((size_t)c * 8 + sh) * 16 + b) * NR + n) * 32 + smh * 16;
        #pragma unroll
        for (int j = 0; j < 16; ++j) o[j] += w * (float)src[j];
    }
    const float invL = 1.f / L;
    #pragma unroll
    for (int j = 0; j < 16; ++j) o[j] *= invL;

    if (oB != nullptr) {
        const float invB = 1.f / mlB[(((size_t)sh * 16 + b) * NR + n) * 2 + 1];
        const f16* src = oB + (((size_t)sh * 16 + b) * NR + n) * 32 + smh * 16;
        #pragma unroll
        for (int j = 0; j < 16; ++j) o[j] += invB * (float)src[j];
    }
    float* dst = HE + ((size_t)b * 512 + q_off + n) * 256 + sh * 32 + smh * 16;
    #pragma unroll
    for (int j4 = 0; j4 < 4; ++j4)
        *(float4*)(dst + j4 * 4) = make_float4(o[j4*4+0], o[j4*4+1], o[j4*4+2], o[j4*4+3]);
}

// ---------------------------------------------------------------------------
extern "C" void kernel_launch(void* const* d_in, const int* in_sizes, int n_in,
                              void* d_out, int out_size, void* d_ws, size_t ws_size,
                              hipStream_t stream)
{
    (void)in_sizes; (void)n_in; (void)out_size; (void)ws_size;

    const float* h_fea  = (const float*)d_in[0];
    const float* aux    = (const float*)d_in[1];
    const float* Wq_c   = (const float*)d_in[2];
    const float* Wq_c1  = (const float*)d_in[3];
    const float* Wk_c   = (const float*)d_in[4];
    const float* Wv_c   = (const float*)d_in[5];
    const float* Wq_ch1 = (const float*)d_in[6];
    const float* Wk_ch  = (const float*)d_in[7];
    const float* Wv_ch  = (const float*)d_in[8];
    const float* W1     = (const float*)d_in[9];
    const float* b1     = (const float*)d_in[10];
    const float* W2     = (const float*)d_in[11];
    const float* b2     = (const float*)d_in[12];
    const float* W_out  = (const float*)d_in[13];

    const size_t TBIG = (size_t)8 * 16 * 448 * 32;   // 1,835,008 elems
    const size_t TSML = (size_t)8 * 16 * 64 * 32;    //   262,144 elems
    char* wp = (char*)d_ws;
    auto alloc = [&](size_t bytes) { char* p = wp; wp += (bytes + 255) & ~(size_t)255; return p; };

    f16*   QT1 = (f16*)alloc(TBIG * 2);
    f16*   QT  = (f16*)alloc(TBIG * 2);
    f16*   KC  = (f16*)alloc(TBIG * 2);
    f16*   VCT = (f16*)alloc(TBIG * 2);              // V_c transposed [h][b][e][448]
    f16*   QS  = (f16*)alloc(TSML * 2);
    f16*   KS  = (f16*)alloc(TSML * 2);
    f16*   VST = (f16*)alloc(TSML * 2);              // V_s transposed [h][b][e][64]
    float* HE  = (float*)alloc((size_t)16 * 512 * 256 * 4);
    f16*   oA  = (f16*)alloc(7 * TBIG * 2);
    float* mlA = (float*)alloc((size_t)7 * 8 * 16 * 448 * 2 * 4);
    f16*   oB  = (f16*)alloc(TBIG * 2);
    float* mlB = (float*)alloc((size_t)8 * 16 * 448 * 2 * 4);
    f16*   oC  = (f16*)alloc(7 * TSML * 2);
    float* mlC = (float*)alloc((size_t)7 * 8 * 16 * 64 * 2 * 4);

    // Projections (task rows q 64..511, stat rows q 0..63); V outputs transposed
    proj_gemm<<<dim3(112, 16), 256, 0, stream>>>(h_fea, Wq_c1, Wq_c, Wk_c, Wv_c,
                                                 QT1, QT, KC, VCT, 64, 448, 7, 3);
    proj_gemm<<<dim3(16, 12), 256, 0, stream>>>(h_fea, Wq_ch1, Wk_ch, Wv_ch, Wv_ch,
                                                QS, KS, VST, VST, 0, 64, 1, 2);

    // attend1: task q vs task k (448 keys, 7 chunks of 64)
    attend_mfma<<<dim3(28, 16, 7), 256, 0, stream>>>(QT1, KC, VCT, aux, W1, b1, W2, b2,
                                                     oA, mlA, 448, 448, 64, 64, 64);
    // attend2: task q vs stat k (64 keys, 1 chunk)
    attend_mfma<<<dim3(28, 16, 1), 256, 0, stream>>>(QT, KS, VST, aux, W1, b1, W2, b2,
                                                     oB, mlB, 448, 64, 64, 64, 0);
    // attend3: stat q vs task k (448 keys, 7 chunks of 64)
    attend_mfma<<<dim3(4, 16, 7), 256, 0, stream>>>(QS, KC, VCT, aux, W1, b1, W2, b2,
                                                    oC, mlC, 64, 448, 64, 0, 64);

    // Combine
    combine_kernel<<<dim3(28, 16), 256, 0, stream>>>(oA, mlA, 7, oB, mlB, HE, 448, 64);
    combine_kernel<<<dim3(4, 16), 256, 0, stream>>>(oC, mlC, 7, nullptr, nullptr, HE, 64, 0);

    // h_wave = HEADS[8192,256] @ W_out[256,256]
    out_gemm<<<dim3(128, 4), 256, 0, stream>>>(HE, W_out, (float*)d_out);
}